// Round 7
// baseline (717.501 us; speedup 1.0000x reference)
//
#include <hip/hip_runtime.h>
#include <cstdint>
#include <cstddef>

#define DN 128
#define NND 50000
#define NED 512000
#define NSCAN 49   // ceil(NND/1024)

typedef __attribute__((ext_vector_type(8))) short bf8;
typedef __attribute__((ext_vector_type(4))) float f4;
typedef unsigned short us;

__device__ __forceinline__ us f2bf(float f){
  union { float f; unsigned int u; } c; c.f = f;
  unsigned int r = c.u + 0x7fffu + ((c.u >> 16) & 1u);
  return (us)(r >> 16);
}
__device__ __forceinline__ float bf2f(us u){
  union { unsigned int u; float f; } c; c.u = ((unsigned int)u) << 16;
  return c.f;
}
// mish(x) = x*tanh(softplus(x)) = x*(u^2-1)/(u^2+1), u = 1+exp(x)
__device__ __forceinline__ float mishf(float x){
  float e = __expf(x);
  float u = 1.f + e;
  float u2 = u * u;
  float t = (u2 - 1.f) / (u2 + 1.f);
  return x * ((x > 20.f) ? 1.f : t);
}

#define MFMA16(a, b, c) __builtin_amdgcn_mfma_f32_16x16x32_bf16((a), (b), (c), 0, 0, 0)

// LDS fragment read: row-major [rows][K] bf16 with (row&7)<<4 byte XOR swizzle.
__device__ __forceinline__ bf8 lds_frag(const us* base, int row, int rowStrideB, int kElem){
  int byte = row * rowStrideB + kElem * 2;
  byte ^= (row & 7) << 4;
  return *(const bf8*)((const char*)base + byte);
}
// Global weight fragment: W^T stored [Nout][K] bf16, plain row-major.
__device__ __forceinline__ bf8 gfrag(const us* W, int n, int K, int kElem){
  return *(const bf8*)(W + (size_t)n * K + kElem);
}

// ---- wave-local 16-row x 128-col primitives (no cross-wave sync anywhere) ----

// acc[ct] covers cols ct*16+s, rows g*4+reg. A-frags: row=s, k=g*8+kk*32.
__device__ __forceinline__ void loadA16(const us* T, int g, int s, bf8 (&a)[4]){
#pragma unroll
  for (int kk = 0; kk < 4; ++kk)
    a[kk] = lds_frag(T, s, 256, kk*32 + g*8);
}

__device__ __forceinline__ void gemm8(const bf8 (&a)[4], const us* __restrict__ WT,
                                      const float* __restrict__ bias,
                                      int g, int s, f4 (&acc)[8]){
#pragma unroll
  for (int ct = 0; ct < 8; ++ct){
    float bv = bias ? bias[ct*16 + s] : 0.f;
    f4 t = {bv, bv, bv, bv};
    acc[ct] = t;
  }
#pragma unroll
  for (int ct = 0; ct < 8; ++ct){
    int n = ct*16 + s;
#pragma unroll
    for (int kk = 0; kk < 4; ++kk)
      acc[ct] = MFMA16(a[kk], gfrag(WT, n, DN, kk*32 + g*8), acc[ct]);
  }
}

// LayerNorm over the 128-wide row entirely in-wave: row = (g,reg), cols = ct (regs) x s (lanes).
__device__ __forceinline__ void ln_mish8(f4 (&acc)[8],
                                         const float* __restrict__ gam,
                                         const float* __restrict__ bet, int s){
  float mu[4], rs[4];
#pragma unroll
  for (int reg = 0; reg < 4; ++reg){
    float sm = 0.f, sq = 0.f;
#pragma unroll
    for (int ct = 0; ct < 8; ++ct){ float v = acc[ct][reg]; sm += v; sq += v*v; }
#pragma unroll
    for (int m = 1; m < 16; m <<= 1){ sm += __shfl_xor(sm, m, 64); sq += __shfl_xor(sq, m, 64); }
    float mm = sm * (1.f/128.f);
    float var = sq * (1.f/128.f) - mm*mm;
    mu[reg] = mm; rs[reg] = rsqrtf(var + 1e-5f);
  }
#pragma unroll
  for (int ct = 0; ct < 8; ++ct){
    float gv = gam[ct*16 + s], bv = bet[ct*16 + s];
#pragma unroll
    for (int reg = 0; reg < 4; ++reg)
      acc[ct][reg] = mishf((acc[ct][reg] - mu[reg]) * rs[reg] * gv + bv);
  }
}

__device__ __forceinline__ void mish8(f4 (&acc)[8]){
#pragma unroll
  for (int ct = 0; ct < 8; ++ct)
#pragma unroll
    for (int reg = 0; reg < 4; ++reg)
      acc[ct][reg] = mishf(acc[ct][reg]);
}

// transpose acc -> wave-private LDS tile (MFMA A layout for the next GEMM)
__device__ __forceinline__ void writeT16(us* T, int g, int s, const f4 (&A)[8]){
#pragma unroll
  for (int ct = 0; ct < 8; ++ct)
#pragma unroll
    for (int reg = 0; reg < 4; ++reg){
      int row = g*4 + reg, col = ct*16 + s;
      int byte = row*256 + col*2; byte ^= (row & 7) << 4;
      *(us*)((char*)T + byte) = f2bf(A[ct][reg]);
    }
}

template<int OUT_BF16>
__device__ __forceinline__ void store16(void* outp, int row0, int g, int s, int ostride,
                                        const f4 (&A)[8]){
#pragma unroll
  for (int ct = 0; ct < 8; ++ct)
#pragma unroll
    for (int reg = 0; reg < 4; ++reg){
      int row = row0 + g*4 + reg;
      if (row < NND){
        int col = ct*16 + s;
        if constexpr (OUT_BF16 != 0)
          ((us*)outp)[(size_t)row*ostride + col] = f2bf(A[ct][reg]);
        else
          ((float*)outp)[(size_t)row*ostride + col] = A[ct][reg];
      }
    }
}

// ---------- Fused node chains: q, k, m(2 GEMM), b(2 GEMM), c(2 GEMM, no LN) ----------
// Each wave owns 16 rows end-to-end; ZERO __syncthreads.
__global__ __launch_bounds__(256, 2)
void node_fused(const float* __restrict__ X,
                const us* __restrict__ WqT,  const float* __restrict__ bq,
                const float* __restrict__ gq, const float* __restrict__ beq,
                const us* __restrict__ WkT,  const float* __restrict__ bk,
                const float* __restrict__ gk, const float* __restrict__ bek,
                const us* __restrict__ Wm1T, const float* __restrict__ bm1,
                const float* __restrict__ gm, const float* __restrict__ bem,
                const us* __restrict__ Wm2T, const float* __restrict__ bm2,
                const us* __restrict__ Wb1T, const float* __restrict__ bb1,
                const float* __restrict__ gb, const float* __restrict__ beb,
                const us* __restrict__ Wb2T, const float* __restrict__ bb2,
                const us* __restrict__ Wc1T, const float* __restrict__ bc1,
                const us* __restrict__ Wc2T,
                us* __restrict__ qt, us* __restrict__ kmb, float* __restrict__ xout)
{
  __shared__ us Tsh[4][16 * DN];   // per-wave 16x128 bf16 tile (X, then t-tiles)

  const int tid = threadIdx.x;
  const int lane = tid & 63, w = tid >> 6;
  const int g = lane >> 4, s = lane & 15;
  const int r = lane >> 2, c4 = lane & 3;
  const int row0 = blockIdx.x * 64 + w * 16;
  us* T = (us*)Tsh[w];

  { // stage this wave's 16 X rows -> bf16 swizzled LDS
    int grow = row0 + r; if (grow >= NND) grow = NND - 1;
    const f4* sp = (const f4*)(X + (size_t)grow * DN + c4 * 32);
#pragma unroll
    for (int j = 0; j < 4; ++j){
      f4 v0 = sp[2*j], v1 = sp[2*j+1];
      bf8 o;
#pragma unroll
      for (int q = 0; q < 4; ++q){ o[q] = (short)f2bf(v0[q]); o[4+q] = (short)f2bf(v1[q]); }
      int byte = r*256 + c4*64 + j*16; byte ^= (r & 7) << 4;
      *(bf8*)((char*)T + byte) = o;
    }
  }

  bf8 a[4], a2[4];
  loadA16(T, g, s, a);    // X frags held in regs for all 5 chain-heads
  f4 acc[8], acc2[8];

  // ---- q ----
  gemm8(a, WqT, bq, g, s, acc);
  ln_mish8(acc, gq, beq, s);
  store16<1>((void*)qt, row0, g, s, DN, acc);

  // ---- k ----
  gemm8(a, WkT, bk, g, s, acc);
  ln_mish8(acc, gk, bek, s);
  store16<1>((void*)kmb, row0, g, s, 384, acc);

  // ---- m (2 GEMM) ----
  gemm8(a, Wm1T, bm1, g, s, acc);
  ln_mish8(acc, gm, bem, s);
  writeT16(T, g, s, acc);
  loadA16(T, g, s, a2);
  gemm8(a2, Wm2T, bm2, g, s, acc2);
  store16<1>((void*)(kmb + 128), row0, g, s, 384, acc2);

  // ---- b (2 GEMM) ----
  gemm8(a, Wb1T, bb1, g, s, acc);
  ln_mish8(acc, gb, beb, s);
  writeT16(T, g, s, acc);
  loadA16(T, g, s, a2);
  gemm8(a2, Wb2T, bb2, g, s, acc2);
  store16<1>((void*)(kmb + 256), row0, g, s, 384, acc2);

  // ---- c (2 GEMM, no LN) ----
  gemm8(a, Wc1T, bc1, g, s, acc);
  mish8(acc);
  writeT16(T, g, s, acc);
  loadA16(T, g, s, a2);
  gemm8(a2, Wc2T, nullptr, g, s, acc2);
  store16<0>((void*)xout, row0, g, s, DN, acc2);
}

// ---------- CSR build ----------
__global__ void csr_count(const int* __restrict__ dst, int* __restrict__ deg){
  int e = blockIdx.x * 256 + threadIdx.x;
  if (e < NED) atomicAdd(&deg[dst[e]], 1);
}

__global__ __launch_bounds__(1024) void csr_blocksum(const int* __restrict__ deg,
                                                     int* __restrict__ bsum){
  __shared__ int sb[1024];
  int t = threadIdx.x, idx = blockIdx.x * 1024 + t;
  sb[t] = (idx < NND) ? deg[idx] : 0;
  __syncthreads();
  for (int off = 512; off > 0; off >>= 1){
    if (t < off) sb[t] += sb[t + off];
    __syncthreads();
  }
  if (t == 0) bsum[blockIdx.x] = sb[0];
}

__global__ void csr_scanroot(const int* __restrict__ bsum, int* __restrict__ boff){
  if (threadIdx.x == 0){
    int run = 0;
    for (int b = 0; b < NSCAN; ++b){ boff[b] = run; run += bsum[b]; }
  }
}

__global__ __launch_bounds__(1024) void csr_scatter(const int* __restrict__ deg,
                                                    const int* __restrict__ boff,
                                                    int* __restrict__ fillctr){
  __shared__ int ss[1024];
  int t = threadIdx.x, idx = blockIdx.x * 1024 + t;
  int v = (idx < NND) ? deg[idx] : 0;
  ss[t] = v;
  __syncthreads();
  for (int off = 1; off < 1024; off <<= 1){
    int x = (t >= off) ? ss[t - off] : 0;
    __syncthreads();
    ss[t] += x;
    __syncthreads();
  }
  if (idx < NND){
    int p = boff[blockIdx.x] + ss[t] - v;
    fillctr[idx] = p;
  }
}

__global__ void csr_fill(const int* __restrict__ src, const int* __restrict__ dst,
                         int* __restrict__ fillctr,
                         int* __restrict__ ssorted, int* __restrict__ dsorted){
  int e = blockIdx.x * 256 + threadIdx.x;
  if (e < NED){
    int d = dst[e];
    int p = atomicAdd(&fillctr[d], 1);
    ssorted[p] = src[e];
    dsorted[p] = d;
  }
}

// ---------- Edge pass (sorted-by-dst, one 64-edge tile per block, 16 edges per wave).
// Fully wave-local: gather -> rel -> GEMM1 -> in-wave LN -> GEMM2 -> exp ->
// register run-merge by dst -> atomics. ZERO __syncthreads. ----------
__global__ __launch_bounds__(256, 2)
void edge_kernel(const us* __restrict__ qtab,
                 const us* __restrict__ kmb,   // [N][384]: k|m|b
                 const us* __restrict__ W1T,
                 const us* __restrict__ W2T,
                 const float* __restrict__ bw1,
                 const float* __restrict__ gwp,
                 const float* __restrict__ bewp,
                 const float* __restrict__ bw2,
                 const int* __restrict__ ssorted,
                 const int* __restrict__ dsorted,
                 float* __restrict__ hacc,      // [N][128] f32, atomic accumulate
                 float* __restrict__ colsum8)   // [8][128] f32 slices
{
  __shared__ us Tsh[4][16 * DN];   // per-wave tile: rel, then t (reused)

  const int tid = threadIdx.x;
  const int lane = tid & 63, w = tid >> 6;
  const int g = lane >> 4, s = lane & 15;
  const int r = lane >> 2, c4 = lane & 3;

  // XCD-chunked swizzle (R5 pattern: concurrent blocks cover a narrow sorted window)
  const int nchunk = gridDim.x >> 3;
  const int swz = (blockIdx.x & 7) * nchunk + (blockIdx.x >> 3);
  const int e0 = swz * 64 + w * 16;
  us* T = (us*)Tsh[w];

  // gather q[src], k|m|b[dst] for this lane's edge row (4 lanes per row, 32 cols each)
  const int e = e0 + r;
  const int sn = ssorted[e], dn = dsorted[e];
  const bf8* qp = (const bf8*)(qtab + (size_t)sn * DN + c4 * 32);
  const us*  kb = kmb + (size_t)dn * 384 + c4 * 32;
  bf8 qv[4], kv[4], mv[4], bv[4];
#pragma unroll
  for (int j = 0; j < 4; ++j){
    qv[j] = qp[j];
    kv[j] = *(const bf8*)(kb + j*8);
    mv[j] = *(const bf8*)(kb + 128 + j*8);
    bv[j] = *(const bf8*)(kb + 256 + j*8);
  }

  // radial: two-pass (recompute diff) to keep register pressure low
  float ss = 0.f;
#pragma unroll
  for (int j = 0; j < 4; ++j)
#pragma unroll
    for (int q = 0; q < 8; ++q){
      float d = bf2f((us)qv[j][q]) - bf2f((us)kv[j][q]);
      ss += d * d;
    }
  ss += __shfl_xor(ss, 1, 64);
  ss += __shfl_xor(ss, 2, 64);
  float rinv = rsqrtf(ss + 1e-8f);

#pragma unroll
  for (int j = 0; j < 4; ++j){
    bf8 o;
#pragma unroll
    for (int q = 0; q < 8; ++q){
      float d = bf2f((us)qv[j][q]) - bf2f((us)kv[j][q]);
      float v = d * rinv * bf2f((us)mv[j][q]) + bf2f((us)bv[j][q]);
      o[q] = (short)f2bf(v);
    }
    int byte = r*256 + c4*64 + j*16; byte ^= (r & 7) << 4;
    *(bf8*)((char*)T + byte) = o;
  }

  // GEMM1 (wave-local)
  bf8 a[4];
  loadA16(T, g, s, a);
  f4 acc[8];
  gemm8(a, W1T, bw1, g, s, acc);

  // LN + mish fully in-wave
  ln_mish8(acc, gwp, bewp, s);

  // t -> T (reuse), GEMM2
  writeT16(T, g, s, acc);
  bf8 a2[4];
  loadA16(T, g, s, a2);
  f4 p[8];
  gemm8(a2, W2T, bw2, g, s, p);
#pragma unroll
  for (int ct = 0; ct < 8; ++ct)
#pragma unroll
    for (int reg = 0; reg < 4; ++reg)
      p[ct][reg] = __expf(p[ct][reg]);

  // dst for this thread's 4 consecutive rows (g*4+reg), via in-wave broadcast
  const int d0 = __shfl(dn, (g*4 + 0) * 4, 64);
  const int d1 = __shfl(dn, (g*4 + 1) * 4, 64);
  const int d2 = __shfl(dn, (g*4 + 2) * 4, 64);
  const int d3 = __shfl(dn, (g*4 + 3) * 4, 64);

  const int cslice = (blockIdx.x & 7) * DN;
#pragma unroll
  for (int ct = 0; ct < 8; ++ct){
    int col = ct*16 + s;
    // register run-merge over 4 consecutive sorted edges
    float run = p[ct][0]; int prev = d0;
    if (d1 != prev){ atomicAdd(&hacc[(size_t)prev * DN + col], run); run = p[ct][1]; prev = d1; }
    else run += p[ct][1];
    if (d2 != prev){ atomicAdd(&hacc[(size_t)prev * DN + col], run); run = p[ct][2]; prev = d2; }
    else run += p[ct][2];
    if (d3 != prev){ atomicAdd(&hacc[(size_t)prev * DN + col], run); run = p[ct][3]; prev = d3; }
    else run += p[ct][3];
    atomicAdd(&hacc[(size_t)prev * DN + col], run);

    // colsum: reduce across g-groups in-wave, one atomic per column per wave
    float cs = p[ct][0] + p[ct][1] + p[ct][2] + p[ct][3];
    cs += __shfl_xor(cs, 16, 64);
    cs += __shfl_xor(cs, 32, 64);
    if (g == 0) atomicAdd(&colsum8[cslice + col], cs);
  }
}

// ---------- final: h = mish(concat[node_feat, hacc/colsum] @ Wn1 + bn1) @ Wn2 + bn2 ----------
// Wave-local except the single rcs barrier.
__global__ __launch_bounds__(256, 2)
void final_h(const float* __restrict__ nodef,
             const float* __restrict__ hacc,
             const float* __restrict__ colsum8,
             const us* __restrict__ Wn1T,
             const float* __restrict__ bn1,
             const us* __restrict__ Wn2T,
             const float* __restrict__ bn2,
             float* __restrict__ outh)
{
  __shared__ us Csh[4][16 * 256];  // per-wave 16x256 concat tile (stride 512B)
  __shared__ float rcs[DN];

  const int tid = threadIdx.x;
  const int lane = tid & 63, w = tid >> 6;
  const int g = lane >> 4, s = lane & 15;
  const int r = lane >> 2, c4 = lane & 3;
  const int row0 = blockIdx.x * 64 + w * 16;
  us* C = (us*)Csh[w];

  if (tid < DN){
    float ssum = 0.f;
#pragma unroll
    for (int x = 0; x < 8; ++x) ssum += colsum8[x * DN + tid];
    rcs[tid] = 1.f / ssum;
  }
  __syncthreads();

  { // stage node_feat -> cols 0..127, hacc*rcs -> cols 128..255
    int grow = row0 + r; if (grow >= NND) grow = NND - 1;
    const f4* np = (const f4*)(nodef + (size_t)grow * DN + c4 * 32);
    const f4* hp = (const f4*)(hacc + (size_t)grow * DN + c4 * 32);
#pragma unroll
    for (int j = 0; j < 4; ++j){
      f4 v0 = np[2*j], v1 = np[2*j+1];
      bf8 o;
#pragma unroll
      for (int q = 0; q < 4; ++q){ o[q] = (short)f2bf(v0[q]); o[4+q] = (short)f2bf(v1[q]); }
      int byte = r*512 + c4*64 + j*16; byte ^= (r & 7) << 4;
      *(bf8*)((char*)C + byte) = o;
      f4 h0 = hp[2*j], h1 = hp[2*j+1];
      bf8 o2;
#pragma unroll
      for (int q = 0; q < 4; ++q){
        o2[q]   = (short)f2bf(h0[q] * rcs[c4*32 + j*8 + q]);
        o2[4+q] = (short)f2bf(h1[q] * rcs[c4*32 + j*8 + 4 + q]);
      }
      int byte2 = r*512 + 256 + c4*64 + j*16; byte2 ^= (r & 7) << 4;
      *(bf8*)((char*)C + byte2) = o2;
    }
  }

  // GEMM1 (K=256), wave-local
  bf8 a[8];
#pragma unroll
  for (int kk = 0; kk < 8; ++kk)
    a[kk] = lds_frag(C, s, 512, kk*32 + g*8);

  f4 acc[8];
#pragma unroll
  for (int ct = 0; ct < 8; ++ct){
    float bv = bn1[ct*16 + s]; f4 t = {bv,bv,bv,bv}; acc[ct] = t;
  }
#pragma unroll
  for (int ct = 0; ct < 8; ++ct){
    int n = ct*16 + s;
#pragma unroll
    for (int kk = 0; kk < 8; ++kk)
      acc[ct] = MFMA16(a[kk], gfrag(Wn1T, n, 256, kk*32 + g*8), acc[ct]);
  }
  mish8(acc);

  // t -> C (reuse, 16x128 layout), GEMM2
  writeT16(C, g, s, acc);
  bf8 a2[4];
  loadA16(C, g, s, a2);
  f4 acc2[8];
  gemm8(a2, Wn2T, bn2, g, s, acc2);
  store16<0>((void*)outh, row0, g, s, DN, acc2);
}

struct WPrepArgs {
  const float* w[12];
  us* wt[12];
  int K[12];
};

// W^T bf16: wt[n*K + k] = bf16(W[k*128 + n])
__global__ void prep_weights(WPrepArgs a){
  int widx = blockIdx.y;
  int K = a.K[widx];
  int idx = blockIdx.x * 256 + threadIdx.x;
  if (idx >= DN * K) return;
  int kshift = (K == 256) ? 8 : 7;
  int n = idx >> kshift;
  int k = idx & (K - 1);
  a.wt[widx][idx] = f2bf(a.w[widx][(size_t)k * DN + n]);
}

extern "C" void kernel_launch(void* const* d_in, const int* in_sizes, int n_in,
                              void* d_out, int out_size, void* d_ws, size_t ws_size,
                              hipStream_t stream) {
  const float* node_feat = (const float*)d_in[0];
  const float* coordf    = (const float*)d_in[1];
  const float* Wq  = (const float*)d_in[2];
  const float* bq  = (const float*)d_in[3];
  const float* gq  = (const float*)d_in[4];
  const float* beq = (const float*)d_in[5];
  const float* Wk  = (const float*)d_in[6];
  const float* bk  = (const float*)d_in[7];
  const float* gk  = (const float*)d_in[8];
  const float* bek = (const float*)d_in[9];
  const float* Wm1 = (const float*)d_in[10];
  const float* bm1 = (const float*)d_in[11];
  const float* gm  = (const float*)d_in[12];
  const float* bem = (const float*)d_in[13];
  const float* Wm2 = (const float*)d_in[14];
  const float* bm2 = (const float*)d_in[15];
  const float* Wb1 = (const float*)d_in[16];
  const float* bb1 = (const float*)d_in[17];
  const float* gb  = (const float*)d_in[18];
  const float* beb = (const float*)d_in[19];
  const float* Wb2 = (const float*)d_in[20];
  const float* bb2 = (const float*)d_in[21];
  const float* Ww1 = (const float*)d_in[22];
  const float* bw1 = (const float*)d_in[23];
  const float* gw  = (const float*)d_in[24];
  const float* bew = (const float*)d_in[25];
  const float* Ww2 = (const float*)d_in[26];
  const float* bw2 = (const float*)d_in[27];
  const float* Wn1 = (const float*)d_in[28];
  const float* bn1 = (const float*)d_in[29];
  const float* Wn2 = (const float*)d_in[30];
  const float* bn2 = (const float*)d_in[31];
  const float* Wc1 = (const float*)d_in[32];
  const float* bc1 = (const float*)d_in[33];
  const float* Wc2 = (const float*)d_in[34];
  const int* srcI  = (const int*)d_in[35];
  const int* dstI  = (const int*)d_in[36];

  char* ws = (char*)d_ws;
  size_t off = 0;
  auto alloc = [&](size_t bytes) -> char* {
    char* p = ws + off;
    off += (bytes + 255) & ~(size_t)255;
    return p;
  };
  us*    qt      = (us*)alloc((size_t)NND * DN * 2);
  us*    kmb     = (us*)alloc((size_t)NND * 384 * 2);
  float* hacc    = (float*)alloc((size_t)NND * DN * 4);
  float* colsum8 = (float*)alloc(8 * DN * 4);
  int*   deg     = (int*)alloc((size_t)NND * 4);
  int*   fillctr = (int*)alloc((size_t)NND * 4);
  int*   ssorted = (int*)alloc((size_t)NED * 4);
  int*   dsorted = (int*)alloc((size_t)NED * 4);
  int*   bsum    = (int*)alloc((size_t)NSCAN * 4);
  int*   boff    = (int*)alloc((size_t)NSCAN * 4);
  us*    wtb     = (us*)alloc((size_t)12 * 16384 * 2);

  // zero the atomic accumulators (hacc + colsum8 are adjacent)
  hipMemsetAsync(hacc, 0, (size_t)NND * DN * 4 + 8 * DN * 4, stream);
  hipMemsetAsync(deg, 0, (size_t)NND * 4, stream);

  WPrepArgs pa;
  const float* wsrc[12] = {Wq, Wk, Wm1, Wm2, Wb1, Wb2, Ww1, Ww2, Wc1, Wc2, Wn2, Wn1};
  for (int i = 0; i < 12; ++i){
    pa.w[i] = wsrc[i];
    pa.wt[i] = wtb + (size_t)i * 16384;
    pa.K[i] = (i == 11) ? 256 : 128;
  }
  prep_weights<<<dim3(128, 12), 256, 0, stream>>>(pa);

  // CSR positions + edge sort by dst
  csr_count<<<(NED + 255) / 256, 256, 0, stream>>>(dstI, deg);
  csr_blocksum<<<NSCAN, 1024, 0, stream>>>(deg, bsum);
  csr_scanroot<<<1, 64, 0, stream>>>(bsum, boff);
  csr_scatter<<<NSCAN, 1024, 0, stream>>>(deg, boff, fillctr);
  csr_fill<<<(NED + 255) / 256, 256, 0, stream>>>(srcI, dstI, fillctr, ssorted, dsorted);

  const int NB = (NND + 63) / 64;  // 782

  node_fused<<<NB, 256, 0, stream>>>(coordf,
      pa.wt[0], bq, gq, beq,
      pa.wt[1], bk, gk, bek,
      pa.wt[2], bm1, gm, bem, pa.wt[3], bm2,
      pa.wt[4], bb1, gb, beb, pa.wt[5], bb2,
      pa.wt[8], bc1, pa.wt[9],
      qt, kmb, (float*)d_out + (size_t)NND * DN);

  edge_kernel<<<NED / 64, 256, 0, stream>>>(qt, kmb, pa.wt[6], pa.wt[7],
                                            bw1, gw, bew, bw2, ssorted, dsorted,
                                            hacc, colsum8);

  final_h<<<NB, 256, 0, stream>>>(node_feat, hacc, colsum8,
                                  pa.wt[11], bn1, pa.wt[10], bn2, (float*)d_out);
}

// Round 8
// 558.277 us; speedup vs baseline: 1.2852x; 1.2852x over previous
//
#include <hip/hip_runtime.h>
#include <cstdint>
#include <cstddef>

#define DN 128
#define NND 50000
#define NED 512000
#define NSCAN 49   // ceil(NND/1024)

typedef __attribute__((ext_vector_type(8))) short bf8;
typedef __attribute__((ext_vector_type(4))) float f4;
typedef unsigned short us;

__device__ __forceinline__ us f2bf(float f){
  union { float f; unsigned int u; } c; c.f = f;
  unsigned int r = c.u + 0x7fffu + ((c.u >> 16) & 1u);
  return (us)(r >> 16);
}
__device__ __forceinline__ float bf2f(us u){
  union { unsigned int u; float f; } c; c.u = ((unsigned int)u) << 16;
  return c.f;
}
// mish(x) = x*tanh(softplus(x)) = x*(u^2-1)/(u^2+1), u = 1+exp(x)
__device__ __forceinline__ float mishf(float x){
  float e = __expf(x);
  float u = 1.f + e;
  float u2 = u * u;
  float t = (u2 - 1.f) / (u2 + 1.f);
  return x * ((x > 20.f) ? 1.f : t);
}

#define MFMA16(a, b, c) __builtin_amdgcn_mfma_f32_16x16x32_bf16((a), (b), (c), 0, 0, 0)

// LDS fragment read: row-major [rows][K] bf16 with (row&7)<<4 byte XOR swizzle.
__device__ __forceinline__ bf8 lds_frag(const us* base, int row, int rowStrideB, int kElem){
  int byte = row * rowStrideB + kElem * 2;
  byte ^= (row & 7) << 4;
  return *(const bf8*)((const char*)base + byte);
}
// Global weight fragment: W^T stored [Nout][K] bf16, plain row-major.
__device__ __forceinline__ bf8 gfrag(const us* W, int n, int K, int kElem){
  return *(const bf8*)(W + (size_t)n * K + kElem);
}

template<int OUT_BF16>
__device__ __forceinline__ void store_tile(void* outp, int nrows, int r0,
                                           int wr, int wc, int g, int s, int ostride,
                                           const f4 (&A)[2][4]){
#pragma unroll
  for (int rt = 0; rt < 2; ++rt)
#pragma unroll
    for (int ct = 0; ct < 4; ++ct)
#pragma unroll
      for (int reg = 0; reg < 4; ++reg){
        int row = r0 + wr*32 + rt*16 + g*4 + reg;
        if (row < nrows){
          int col = wc*64 + ct*16 + s;
          float v = A[rt][ct][reg];
          if constexpr (OUT_BF16 != 0)
            ((us*)outp)[(size_t)row*ostride + col] = f2bf(v);
          else
            ((float*)outp)[(size_t)row*ostride + col] = v;
        }
      }
}

// GEMM: acc = bias + A(regs) @ W^T  (2 row-frags x 4 col-frags; 2x B reuse)
__device__ __forceinline__ void gemm_reg(const bf8 (&a)[2][4], const us* __restrict__ WT,
                                         const float* __restrict__ bias,
                                         int wc, int g, int s, f4 (&acc)[2][4]){
#pragma unroll
  for (int ct = 0; ct < 4; ++ct){
    float bv = bias ? bias[wc*64 + ct*16 + s] : 0.f;
    f4 t = {bv, bv, bv, bv};
    acc[0][ct] = t; acc[1][ct] = t;
  }
#pragma unroll
  for (int ct = 0; ct < 4; ++ct){
    int n = wc*64 + ct*16 + s;
#pragma unroll
    for (int kk = 0; kk < 4; ++kk){
      bf8 b = gfrag(WT, n, DN, kk*32 + g*8);
      acc[0][ct] = MFMA16(a[0][kk], b, acc[0][ct]);
      acc[1][ct] = MFMA16(a[1][kk], b, acc[1][ct]);
    }
  }
}

// LN across the 128-wide row (two waves share a row) + mish. Uses buf parity to
// avoid WAR races on the stats arrays between consecutive chains.
__device__ __forceinline__ void ln_mish(f4 (&acc)[2][4],
                                        const float* __restrict__ gam,
                                        const float* __restrict__ bet,
                                        int wr, int wc, int g, int s,
                                        float (*rowsum)[64][2], float (*rowsq)[64][2],
                                        int buf){
  float gv[4], bev[4];
#pragma unroll
  for (int ct = 0; ct < 4; ++ct){ int n = wc*64 + ct*16 + s; gv[ct] = gam[n]; bev[ct] = bet[n]; }
#pragma unroll
  for (int rt = 0; rt < 2; ++rt)
#pragma unroll
    for (int reg = 0; reg < 4; ++reg){
      float sm = acc[rt][0][reg] + acc[rt][1][reg] + acc[rt][2][reg] + acc[rt][3][reg];
      float sq = acc[rt][0][reg]*acc[rt][0][reg] + acc[rt][1][reg]*acc[rt][1][reg]
               + acc[rt][2][reg]*acc[rt][2][reg] + acc[rt][3][reg]*acc[rt][3][reg];
#pragma unroll
      for (int m = 1; m < 16; m <<= 1){ sm += __shfl_xor(sm, m, 64); sq += __shfl_xor(sq, m, 64); }
      if (s == 0){
        int row = wr*32 + rt*16 + g*4 + reg;
        rowsum[buf][row][wc] = sm; rowsq[buf][row][wc] = sq;
      }
    }
  __syncthreads();
#pragma unroll
  for (int rt = 0; rt < 2; ++rt)
#pragma unroll
    for (int reg = 0; reg < 4; ++reg){
      int row = wr*32 + rt*16 + g*4 + reg;
      float sm = rowsum[buf][row][0] + rowsum[buf][row][1];
      float sq = rowsq[buf][row][0] + rowsq[buf][row][1];
      float mu = sm * (1.f/128.f);
      float var = sq * (1.f/128.f) - mu*mu;
      float rs = rsqrtf(var + 1e-5f);
#pragma unroll
      for (int ct = 0; ct < 4; ++ct)
        acc[rt][ct][reg] = mishf((acc[rt][ct][reg] - mu) * rs * gv[ct] + bev[ct]);
    }
}

__device__ __forceinline__ void write_T(us* Tsh, int wr, int wc, int g, int s,
                                        const f4 (&A)[2][4]){
#pragma unroll
  for (int rt = 0; rt < 2; ++rt)
#pragma unroll
    for (int ct = 0; ct < 4; ++ct)
#pragma unroll
      for (int reg = 0; reg < 4; ++reg){
        int row = wr*32 + rt*16 + g*4 + reg;
        int col = wc*64 + ct*16 + s;
        int byte = row*256 + col*2; byte ^= (row & 7) << 4;
        *(us*)((char*)Tsh + byte) = f2bf(A[rt][ct][reg]);
      }
}

__device__ __forceinline__ void load_a2(const us* Tsh, int wr, int g, int s, bf8 (&a2)[2][4]){
#pragma unroll
  for (int rt = 0; rt < 2; ++rt)
#pragma unroll
    for (int kk = 0; kk < 4; ++kk)
      a2[rt][kk] = lds_frag(Tsh, wr*32 + rt*16 + s, 256, kk*32 + g*8);
}

// ---- wave-local 16-row x 128-col primitives for the edge kernel ----
__device__ __forceinline__ void loadA16(const us* T, int g, int s, bf8 (&a)[4]){
#pragma unroll
  for (int kk = 0; kk < 4; ++kk)
    a[kk] = lds_frag(T, s, 256, kk*32 + g*8);
}

__device__ __forceinline__ void gemm8(const bf8 (&a)[4], const us* __restrict__ WT,
                                      const float* __restrict__ bias,
                                      int g, int s, f4 (&acc)[8]){
#pragma unroll
  for (int ct = 0; ct < 8; ++ct){
    float bv = bias ? bias[ct*16 + s] : 0.f;
    f4 t = {bv, bv, bv, bv};
    acc[ct] = t;
  }
#pragma unroll
  for (int ct = 0; ct < 8; ++ct){
    int n = ct*16 + s;
#pragma unroll
    for (int kk = 0; kk < 4; ++kk)
      acc[ct] = MFMA16(a[kk], gfrag(WT, n, DN, kk*32 + g*8), acc[ct]);
  }
}

// LayerNorm over the 128-wide row entirely in-wave.
__device__ __forceinline__ void ln_mish8(f4 (&acc)[8],
                                         const float* __restrict__ gam,
                                         const float* __restrict__ bet, int s){
  float mu[4], rs[4];
#pragma unroll
  for (int reg = 0; reg < 4; ++reg){
    float sm = 0.f, sq = 0.f;
#pragma unroll
    for (int ct = 0; ct < 8; ++ct){ float v = acc[ct][reg]; sm += v; sq += v*v; }
#pragma unroll
    for (int m = 1; m < 16; m <<= 1){ sm += __shfl_xor(sm, m, 64); sq += __shfl_xor(sq, m, 64); }
    float mm = sm * (1.f/128.f);
    float var = sq * (1.f/128.f) - mm*mm;
    mu[reg] = mm; rs[reg] = rsqrtf(var + 1e-5f);
  }
#pragma unroll
  for (int ct = 0; ct < 8; ++ct){
    float gv = gam[ct*16 + s], bv = bet[ct*16 + s];
#pragma unroll
    for (int reg = 0; reg < 4; ++reg)
      acc[ct][reg] = mishf((acc[ct][reg] - mu[reg]) * rs[reg] * gv + bv);
  }
}

__device__ __forceinline__ void writeT16(us* T, int g, int s, const f4 (&A)[8]){
#pragma unroll
  for (int ct = 0; ct < 8; ++ct)
#pragma unroll
    for (int reg = 0; reg < 4; ++reg){
      int row = g*4 + reg, col = ct*16 + s;
      int byte = row*256 + col*2; byte ^= (row & 7) << 4;
      *(us*)((char*)T + byte) = f2bf(A[ct][reg]);
    }
}

// ---------- Fused node chains (R5 structure: 64-row block, 2x2 waves, 2x B reuse) ----------
__global__ __launch_bounds__(256, 2)
void node_fused(const float* __restrict__ X,
                const us* __restrict__ WqT,  const float* __restrict__ bq,
                const float* __restrict__ gq, const float* __restrict__ beq,
                const us* __restrict__ WkT,  const float* __restrict__ bk,
                const float* __restrict__ gk, const float* __restrict__ bek,
                const us* __restrict__ Wm1T, const float* __restrict__ bm1,
                const float* __restrict__ gm, const float* __restrict__ bem,
                const us* __restrict__ Wm2T, const float* __restrict__ bm2,
                const us* __restrict__ Wb1T, const float* __restrict__ bb1,
                const float* __restrict__ gb, const float* __restrict__ beb,
                const us* __restrict__ Wb2T, const float* __restrict__ bb2,
                const us* __restrict__ Wc1T, const float* __restrict__ bc1,
                const us* __restrict__ Wc2T,
                us* __restrict__ qt, us* __restrict__ kmb, float* __restrict__ xout)
{
  __shared__ us Ash[64 * DN];
  __shared__ float rowsum[2][64][2];
  __shared__ float rowsq[2][64][2];

  const int tid = threadIdx.x;
  const int r0 = blockIdx.x * 64;

  { // stage X rows -> bf16 swizzled LDS (once, shared by 8 GEMMs)
    int r = tid >> 2, c4 = tid & 3;
    int grow = r0 + r; if (grow >= NND) grow = NND - 1;
    const f4* sp = (const f4*)(X + (size_t)grow * DN + c4 * 32);
#pragma unroll
    for (int j = 0; j < 4; ++j){
      f4 v0 = sp[2*j], v1 = sp[2*j+1];
      bf8 o;
#pragma unroll
      for (int q = 0; q < 4; ++q){ o[q] = (short)f2bf(v0[q]); o[4+q] = (short)f2bf(v1[q]); }
      int byte = r*256 + c4*64 + j*16; byte ^= (r & 7) << 4;
      *(bf8*)((char*)Ash + byte) = o;
    }
  }
  __syncthreads();

  const int lane = tid & 63, w = tid >> 6;
  const int wr = w >> 1, wc = w & 1;
  const int g = lane >> 4, s = lane & 15;

  bf8 a[2][4];
#pragma unroll
  for (int rt = 0; rt < 2; ++rt)
#pragma unroll
    for (int kk = 0; kk < 4; ++kk)
      a[rt][kk] = lds_frag(Ash, wr*32 + rt*16 + s, 256, kk*32 + g*8);
  __syncthreads();   // all A-frag reads done -> Ash reusable as T

  f4 acc[2][4], acc2[2][4];
  bf8 a2[2][4];

  // ---- q ----
  gemm_reg(a, WqT, bq, wc, g, s, acc);
  ln_mish(acc, gq, beq, wr, wc, g, s, rowsum, rowsq, 0);
  store_tile<1>((void*)qt, NND, r0, wr, wc, g, s, DN, acc);

  // ---- k ----
  gemm_reg(a, WkT, bk, wc, g, s, acc);
  ln_mish(acc, gk, bek, wr, wc, g, s, rowsum, rowsq, 1);
  store_tile<1>((void*)kmb, NND, r0, wr, wc, g, s, 384, acc);

  // ---- m (2 GEMM) ----
  gemm_reg(a, Wm1T, bm1, wc, g, s, acc);
  ln_mish(acc, gm, bem, wr, wc, g, s, rowsum, rowsq, 0);
  write_T(Ash, wr, wc, g, s, acc);
  __syncthreads();
  load_a2(Ash, wr, g, s, a2);
#pragma unroll
  for (int ct = 0; ct < 4; ++ct){
    float bv = bm2[wc*64 + ct*16 + s]; f4 t = {bv,bv,bv,bv}; acc2[0][ct] = t; acc2[1][ct] = t;
  }
#pragma unroll
  for (int ct = 0; ct < 4; ++ct){
    int n = wc*64 + ct*16 + s;
#pragma unroll
    for (int kk = 0; kk < 4; ++kk){
      bf8 b = gfrag(Wm2T, n, DN, kk*32 + g*8);
      acc2[0][ct] = MFMA16(a2[0][kk], b, acc2[0][ct]);
      acc2[1][ct] = MFMA16(a2[1][kk], b, acc2[1][ct]);
    }
  }
  store_tile<1>((void*)(kmb + 128), NND, r0, wr, wc, g, s, 384, acc2);

  // ---- b (2 GEMM) ----
  gemm_reg(a, Wb1T, bb1, wc, g, s, acc);
  ln_mish(acc, gb, beb, wr, wc, g, s, rowsum, rowsq, 1);
  write_T(Ash, wr, wc, g, s, acc);
  __syncthreads();
  load_a2(Ash, wr, g, s, a2);
#pragma unroll
  for (int ct = 0; ct < 4; ++ct){
    float bv = bb2[wc*64 + ct*16 + s]; f4 t = {bv,bv,bv,bv}; acc2[0][ct] = t; acc2[1][ct] = t;
  }
#pragma unroll
  for (int ct = 0; ct < 4; ++ct){
    int n = wc*64 + ct*16 + s;
#pragma unroll
    for (int kk = 0; kk < 4; ++kk){
      bf8 b = gfrag(Wb2T, n, DN, kk*32 + g*8);
      acc2[0][ct] = MFMA16(a2[0][kk], b, acc2[0][ct]);
      acc2[1][ct] = MFMA16(a2[1][kk], b, acc2[1][ct]);
    }
  }
  store_tile<1>((void*)(kmb + 256), NND, r0, wr, wc, g, s, 384, acc2);

  // ---- c (2 GEMM, no LN) ----
  gemm_reg(a, Wc1T, bc1, wc, g, s, acc);
#pragma unroll
  for (int rt = 0; rt < 2; ++rt)
#pragma unroll
    for (int ct = 0; ct < 4; ++ct)
#pragma unroll
      for (int reg = 0; reg < 4; ++reg)
        acc[rt][ct][reg] = mishf(acc[rt][ct][reg]);
  __syncthreads();
  write_T(Ash, wr, wc, g, s, acc);
  __syncthreads();
  load_a2(Ash, wr, g, s, a2);
#pragma unroll
  for (int ct = 0; ct < 4; ++ct){ f4 t = {0,0,0,0}; acc2[0][ct] = t; acc2[1][ct] = t; }
#pragma unroll
  for (int ct = 0; ct < 4; ++ct){
    int n = wc*64 + ct*16 + s;
#pragma unroll
    for (int kk = 0; kk < 4; ++kk){
      bf8 b = gfrag(Wc2T, n, DN, kk*32 + g*8);
      acc2[0][ct] = MFMA16(a2[0][kk], b, acc2[0][ct]);
      acc2[1][ct] = MFMA16(a2[1][kk], b, acc2[1][ct]);
    }
  }
  store_tile<0>((void*)xout, NND, r0, wr, wc, g, s, DN, acc2);
}

// ---------- CSR build ----------
__global__ void csr_count(const int* __restrict__ dst, int* __restrict__ deg){
  int e = blockIdx.x * 256 + threadIdx.x;
  if (e < NED) atomicAdd(&deg[dst[e]], 1);
}

__global__ __launch_bounds__(1024) void csr_blocksum(const int* __restrict__ deg,
                                                     int* __restrict__ bsum){
  __shared__ int sb[1024];
  int t = threadIdx.x, idx = blockIdx.x * 1024 + t;
  sb[t] = (idx < NND) ? deg[idx] : 0;
  __syncthreads();
  for (int off = 512; off > 0; off >>= 1){
    if (t < off) sb[t] += sb[t + off];
    __syncthreads();
  }
  if (t == 0) bsum[blockIdx.x] = sb[0];
}

__global__ void csr_scanroot(const int* __restrict__ bsum, int* __restrict__ boff){
  if (threadIdx.x == 0){
    int run = 0;
    for (int b = 0; b < NSCAN; ++b){ boff[b] = run; run += bsum[b]; }
  }
}

__global__ __launch_bounds__(1024) void csr_scatter(const int* __restrict__ deg,
                                                    const int* __restrict__ boff,
                                                    int* __restrict__ fillctr){
  __shared__ int ss[1024];
  int t = threadIdx.x, idx = blockIdx.x * 1024 + t;
  int v = (idx < NND) ? deg[idx] : 0;
  ss[t] = v;
  __syncthreads();
  for (int off = 1; off < 1024; off <<= 1){
    int x = (t >= off) ? ss[t - off] : 0;
    __syncthreads();
    ss[t] += x;
    __syncthreads();
  }
  if (idx < NND){
    int p = boff[blockIdx.x] + ss[t] - v;
    fillctr[idx] = p;
  }
}

__global__ void csr_fill(const int* __restrict__ src, const int* __restrict__ dst,
                         int* __restrict__ fillctr,
                         int* __restrict__ ssorted, int* __restrict__ dsorted){
  int e = blockIdx.x * 256 + threadIdx.x;
  if (e < NED){
    int d = dst[e];
    int p = atomicAdd(&fillctr[d], 1);
    ssorted[p] = src[e];
    dsorted[p] = d;
  }
}

// ---------- Edge pass: wave-local compute (zero barriers) + ONE barrier +
// block-level 32-row segment-sum (R5 atomic efficiency). ----------
__global__ __launch_bounds__(256, 2)
void edge_kernel(const us* __restrict__ qtab,
                 const us* __restrict__ kmb,   // [N][384]: k|m|b
                 const us* __restrict__ W1T,
                 const us* __restrict__ W2T,
                 const float* __restrict__ bw1,
                 const float* __restrict__ gwp,
                 const float* __restrict__ bewp,
                 const float* __restrict__ bw2,
                 const int* __restrict__ ssorted,
                 const int* __restrict__ dsorted,
                 float* __restrict__ hacc,      // [N][128] f32, atomic accumulate
                 float* __restrict__ colsum8)   // [8][128] f32 slices
{
  __shared__ us Tsh[4][16 * DN];   // per-wave quadrant: rel -> t -> p
  __shared__ int dsh[64];

  const int tid = threadIdx.x;
  const int lane = tid & 63, w = tid >> 6;
  const int g = lane >> 4, s = lane & 15;
  const int r = lane >> 2, c4 = lane & 3;

  // XCD-chunked swizzle (concurrent blocks cover a narrow sorted window)
  const int nchunk = gridDim.x >> 3;
  const int swz = (blockIdx.x & 7) * nchunk + (blockIdx.x >> 3);
  const int e0 = swz * 64 + w * 16;
  us* T = (us*)Tsh[w];

  // gather q[src], k|m|b[dst] for this lane's edge row (4 lanes/row, 32 cols each)
  const int e = e0 + r;
  const int sn = ssorted[e], dn = dsorted[e];
  const bf8* qp = (const bf8*)(qtab + (size_t)sn * DN + c4 * 32);
  const us*  kb = kmb + (size_t)dn * 384 + c4 * 32;
  bf8 qv[4], kv[4], mv[4], bv[4];
#pragma unroll
  for (int j = 0; j < 4; ++j){
    qv[j] = qp[j];
    kv[j] = *(const bf8*)(kb + j*8);
    mv[j] = *(const bf8*)(kb + 128 + j*8);
    bv[j] = *(const bf8*)(kb + 256 + j*8);
  }
  if (c4 == 0) dsh[w*16 + r] = dn;

  // radial (two-pass diff to limit register pressure)
  float ss = 0.f;
#pragma unroll
  for (int j = 0; j < 4; ++j)
#pragma unroll
    for (int q = 0; q < 8; ++q){
      float d = bf2f((us)qv[j][q]) - bf2f((us)kv[j][q]);
      ss += d * d;
    }
  ss += __shfl_xor(ss, 1, 64);
  ss += __shfl_xor(ss, 2, 64);
  float rinv = rsqrtf(ss + 1e-8f);

#pragma unroll
  for (int j = 0; j < 4; ++j){
    bf8 o;
#pragma unroll
    for (int q = 0; q < 8; ++q){
      float d = bf2f((us)qv[j][q]) - bf2f((us)kv[j][q]);
      float v = d * rinv * bf2f((us)mv[j][q]) + bf2f((us)bv[j][q]);
      o[q] = (short)f2bf(v);
    }
    int byte = r*256 + c4*64 + j*16; byte ^= (r & 7) << 4;
    *(bf8*)((char*)T + byte) = o;
  }

  // GEMM1 (wave-local) -> in-wave LN+mish -> GEMM2 -> exp
  bf8 a[4];
  loadA16(T, g, s, a);
  f4 acc[8];
  gemm8(a, W1T, bw1, g, s, acc);
  ln_mish8(acc, gwp, bewp, s);
  writeT16(T, g, s, acc);
  bf8 a2[4];
  loadA16(T, g, s, a2);
  f4 p[8];
  gemm8(a2, W2T, bw2, g, s, p);
#pragma unroll
  for (int ct = 0; ct < 8; ++ct)
#pragma unroll
    for (int reg = 0; reg < 4; ++reg)
      p[ct][reg] = __expf(p[ct][reg]);

  // p -> wave quadrant (wave-synchronous overwrite; LDS ops in-order per wave)
  writeT16(T, g, s, p);
  __syncthreads();   // the ONE block barrier

  { // block-level segment-sum over the 64 sorted edges (R5 pattern):
    // thread owns column (tid&127), rows [half*32, half*32+32).
    int col = tid & 127, half = tid >> 7;
    int rbeg = half * 32;
    float csum = 0.f;
    int prev = dsh[rbeg];
    float run = 0.f;
#pragma unroll 8
    for (int r2 = rbeg; r2 < rbeg + 32; ++r2){
      int qw = r2 >> 4, lr = r2 & 15;
      int byte = lr*256 + col*2; byte ^= (lr & 7) << 4;
      float v = bf2f(*(const us*)((const char*)Tsh[qw] + byte));
      int d = dsh[r2];
      csum += v;
      if (d != prev){
        atomicAdd(&hacc[(size_t)prev * DN + col], run);
        run = v; prev = d;
      } else {
        run += v;
      }
    }
    atomicAdd(&hacc[(size_t)prev * DN + col], run);
    atomicAdd(&colsum8[(blockIdx.x & 7) * DN + col], csum);
  }
}

// ---------- final: h = mish(concat[node_feat, hacc/colsum] @ Wn1 + bn1) @ Wn2 + bn2 ----------
__global__ __launch_bounds__(256, 2)
void final_h(const float* __restrict__ nodef,
             const float* __restrict__ hacc,
             const float* __restrict__ colsum8,
             const us* __restrict__ Wn1T,
             const float* __restrict__ bn1,
             const us* __restrict__ Wn2T,
             const float* __restrict__ bn2,
             float* __restrict__ outh)
{
  __shared__ us Ash[64 * 256];   // [64 rows][256 cols] bf16, stride 512B
  __shared__ float rcs[DN];      // 1/colsum per column

  const int tid = threadIdx.x;
  const int r0 = blockIdx.x * 64;

  if (tid < DN){
    float ssum = 0.f;
#pragma unroll
    for (int x = 0; x < 8; ++x) ssum += colsum8[x * DN + tid];
    rcs[tid] = 1.f / ssum;
  }
  __syncthreads();

  { // stage node_feat -> cols 0..127, hacc*rcs -> cols 128..255
    int r = tid >> 2, c4 = tid & 3;
    int grow = r0 + r; if (grow >= NND) grow = NND - 1;
    const f4* np = (const f4*)(nodef + (size_t)grow * DN + c4 * 32);
    const f4* hp = (const f4*)(hacc + (size_t)grow * DN + c4 * 32);
#pragma unroll
    for (int j = 0; j < 4; ++j){
      f4 v0 = np[2*j], v1 = np[2*j+1];
      bf8 o;
#pragma unroll
      for (int q = 0; q < 4; ++q){ o[q] = (short)f2bf(v0[q]); o[4+q] = (short)f2bf(v1[q]); }
      int byte = r*512 + c4*64 + j*16; byte ^= (r & 7) << 4;
      *(bf8*)((char*)Ash + byte) = o;
      f4 h0 = hp[2*j], h1 = hp[2*j+1];
      bf8 o2;
#pragma unroll
      for (int q = 0; q < 4; ++q){
        o2[q]   = (short)f2bf(h0[q] * rcs[c4*32 + j*8 + q]);
        o2[4+q] = (short)f2bf(h1[q] * rcs[c4*32 + j*8 + 4 + q]);
      }
      int byte2 = r*512 + 256 + c4*64 + j*16; byte2 ^= (r & 7) << 4;
      *(bf8*)((char*)Ash + byte2) = o2;
    }
  }
  __syncthreads();

  const int lane = tid & 63, w = tid >> 6;
  const int wr = w >> 1, wc = w & 1;
  const int g = lane >> 4, s = lane & 15;

  float b1v[4], b2v[4];
#pragma unroll
  for (int ct = 0; ct < 4; ++ct){ int n = wc*64 + ct*16 + s; b1v[ct] = bn1[n]; b2v[ct] = bn2[n]; }

  f4 acc[2][4];
#pragma unroll
  for (int ct = 0; ct < 4; ++ct){ f4 t = {b1v[ct], b1v[ct], b1v[ct], b1v[ct]}; acc[0][ct] = t; acc[1][ct] = t; }

  bf8 a[2][8];
#pragma unroll
  for (int rt = 0; rt < 2; ++rt)
#pragma unroll
    for (int kk = 0; kk < 8; ++kk)
      a[rt][kk] = lds_frag(Ash, wr*32 + rt*16 + s, 512, kk*32 + g*8);
  __syncthreads();   // frag reads done -> Ash reusable as T

#pragma unroll
  for (int ct = 0; ct < 4; ++ct){
    int n = wc*64 + ct*16 + s;
#pragma unroll
    for (int kk = 0; kk < 8; ++kk){
      bf8 b = gfrag(Wn1T, n, 256, kk*32 + g*8);
      acc[0][ct] = MFMA16(a[0][kk], b, acc[0][ct]);
      acc[1][ct] = MFMA16(a[1][kk], b, acc[1][ct]);
    }
  }

#pragma unroll
  for (int rt = 0; rt < 2; ++rt)
#pragma unroll
    for (int ct = 0; ct < 4; ++ct)
#pragma unroll
      for (int reg = 0; reg < 4; ++reg)
        acc[rt][ct][reg] = mishf(acc[rt][ct][reg]);
  write_T((us*)Ash, wr, wc, g, s, acc);
  __syncthreads();

  f4 acc2[2][4];
#pragma unroll
  for (int ct = 0; ct < 4; ++ct){ f4 t = {b2v[ct], b2v[ct], b2v[ct], b2v[ct]}; acc2[0][ct] = t; acc2[1][ct] = t; }
  bf8 a2[2][4];
  load_a2((const us*)Ash, wr, g, s, a2);
#pragma unroll
  for (int ct = 0; ct < 4; ++ct){
    int n = wc*64 + ct*16 + s;
#pragma unroll
    for (int kk = 0; kk < 4; ++kk){
      bf8 b = gfrag(Wn2T, n, DN, kk*32 + g*8);
      acc2[0][ct] = MFMA16(a2[0][kk], b, acc2[0][ct]);
      acc2[1][ct] = MFMA16(a2[1][kk], b, acc2[1][ct]);
    }
  }
  store_tile<0>((void*)outh, NND, r0, wr, wc, g, s, DN, acc2);
}

struct WPrepArgs {
  const float* w[12];
  us* wt[12];
  int K[12];
};

// W^T bf16: wt[n*K + k] = bf16(W[k*128 + n])
__global__ void prep_weights(WPrepArgs a){
  int widx = blockIdx.y;
  int K = a.K[widx];
  int idx = blockIdx.x * 256 + threadIdx.x;
  if (idx >= DN * K) return;
  int kshift = (K == 256) ? 8 : 7;
  int n = idx >> kshift;
  int k = idx & (K - 1);
  a.wt[widx][idx] = f2bf(a.w[widx][(size_t)k * DN + n]);
}

extern "C" void kernel_launch(void* const* d_in, const int* in_sizes, int n_in,
                              void* d_out, int out_size, void* d_ws, size_t ws_size,
                              hipStream_t stream) {
  const float* node_feat = (const float*)d_in[0];
  const float* coordf    = (const float*)d_in[1];
  const float* Wq  = (const float*)d_in[2];
  const float* bq  = (const float*)d_in[3];
  const float* gq  = (const float*)d_in[4];
  const float* beq = (const float*)d_in[5];
  const float* Wk  = (const float*)d_in[6];
  const float* bk  = (const float*)d_in[7];
  const float* gk  = (const float*)d_in[8];
  const float* bek = (const float*)d_in[9];
  const float* Wm1 = (const float*)d_in[10];
  const float* bm1 = (const float*)d_in[11];
  const float* gm  = (const float*)d_in[12];
  const float* bem = (const float*)d_in[13];
  const float* Wm2 = (const float*)d_in[14];
  const float* bm2 = (const float*)d_in[15];
  const float* Wb1 = (const float*)d_in[16];
  const float* bb1 = (const float*)d_in[17];
  const float* gb  = (const float*)d_in[18];
  const float* beb = (const float*)d_in[19];
  const float* Wb2 = (const float*)d_in[20];
  const float* bb2 = (const float*)d_in[21];
  const float* Ww1 = (const float*)d_in[22];
  const float* bw1 = (const float*)d_in[23];
  const float* gw  = (const float*)d_in[24];
  const float* bew = (const float*)d_in[25];
  const float* Ww2 = (const float*)d_in[26];
  const float* bw2 = (const float*)d_in[27];
  const float* Wn1 = (const float*)d_in[28];
  const float* bn1 = (const float*)d_in[29];
  const float* Wn2 = (const float*)d_in[30];
  const float* bn2 = (const float*)d_in[31];
  const float* Wc1 = (const float*)d_in[32];
  const float* bc1 = (const float*)d_in[33];
  const float* Wc2 = (const float*)d_in[34];
  const int* srcI  = (const int*)d_in[35];
  const int* dstI  = (const int*)d_in[36];

  char* ws = (char*)d_ws;
  size_t off = 0;
  auto alloc = [&](size_t bytes) -> char* {
    char* p = ws + off;
    off += (bytes + 255) & ~(size_t)255;
    return p;
  };
  us*    qt      = (us*)alloc((size_t)NND * DN * 2);
  us*    kmb     = (us*)alloc((size_t)NND * 384 * 2);
  float* hacc    = (float*)alloc((size_t)NND * DN * 4);
  float* colsum8 = (float*)alloc(8 * DN * 4);
  int*   deg     = (int*)alloc((size_t)NND * 4);
  int*   fillctr = (int*)alloc((size_t)NND * 4);
  int*   ssorted = (int*)alloc((size_t)NED * 4);
  int*   dsorted = (int*)alloc((size_t)NED * 4);
  int*   bsum    = (int*)alloc((size_t)NSCAN * 4);
  int*   boff    = (int*)alloc((size_t)NSCAN * 4);
  us*    wtb     = (us*)alloc((size_t)12 * 16384 * 2);

  // zero the atomic accumulators (hacc + colsum8 are adjacent)
  hipMemsetAsync(hacc, 0, (size_t)NND * DN * 4 + 8 * DN * 4, stream);
  hipMemsetAsync(deg, 0, (size_t)NND * 4, stream);

  WPrepArgs pa;
  const float* wsrc[12] = {Wq, Wk, Wm1, Wm2, Wb1, Wb2, Ww1, Ww2, Wc1, Wc2, Wn2, Wn1};
  for (int i = 0; i < 12; ++i){
    pa.w[i] = wsrc[i];
    pa.wt[i] = wtb + (size_t)i * 16384;
    pa.K[i] = (i == 11) ? 256 : 128;
  }
  prep_weights<<<dim3(128, 12), 256, 0, stream>>>(pa);

  // CSR positions + edge sort by dst
  csr_count<<<(NED + 255) / 256, 256, 0, stream>>>(dstI, deg);
  csr_blocksum<<<NSCAN, 1024, 0, stream>>>(deg, bsum);
  csr_scanroot<<<1, 64, 0, stream>>>(bsum, boff);
  csr_scatter<<<NSCAN, 1024, 0, stream>>>(deg, boff, fillctr);
  csr_fill<<<(NED + 255) / 256, 256, 0, stream>>>(srcI, dstI, fillctr, ssorted, dsorted);

  const int NB = (NND + 63) / 64;  // 782

  node_fused<<<NB, 256, 0, stream>>>(coordf,
      pa.wt[0], bq, gq, beq,
      pa.wt[1], bk, gk, bek,
      pa.wt[2], bm1, gm, bem, pa.wt[3], bm2,
      pa.wt[4], bb1, gb, beb, pa.wt[5], bb2,
      pa.wt[8], bc1, pa.wt[9],
      qt, kmb, (float*)d_out + (size_t)NND * DN);

  edge_kernel<<<NED / 64, 256, 0, stream>>>(qt, kmb, pa.wt[6], pa.wt[7],
                                            bw1, gw, bew, bw2, ssorted, dsorted,
                                            hacc, colsum8);

  final_h<<<NB, 256, 0, stream>>>(node_feat, hacc, colsum8,
                                  pa.wt[11], bn1, pa.wt[10], bn2, (float*)d_out);
}